// Round 5
// baseline (757.900 us; speedup 1.0000x reference)
//
#include <hip/hip_runtime.h>

// Problem dims
#define B_ 128
#define T_ 1024
#define I_ 256
#define H_ 512
#define V_ 32000

typedef float  float4v __attribute__((ext_vector_type(4)));
typedef short  short8  __attribute__((ext_vector_type(8)));

__device__ __forceinline__ unsigned short f2bf(float f){
  unsigned int u = __float_as_uint(f);
  u += 0x7fffu + ((u >> 16) & 1u);          // round-to-nearest-even
  return (unsigned short)(u >> 16);
}
__device__ __forceinline__ ushort4 f2bf4(float4 v){
  ushort4 u; u.x=f2bf(v.x); u.y=f2bf(v.y); u.z=f2bf(v.z); u.w=f2bf(v.w); return u;
}
__device__ __forceinline__ unsigned int cvt_pk_bf16(float lo, float hi){
  unsigned int r;
  asm volatile("v_cvt_pk_bf16_f32 %0, %1, %2" : "=v"(r) : "v"(lo), "v"(hi));
  return r;
}
__device__ __forceinline__ float fast_tanh(float x){
  float e = __expf(2.f*x);
  return 1.f - __fdividef(2.f, e + 1.f);
}
__device__ __forceinline__ float fast_sig(float x){
  return __fdividef(1.f, 1.f + __expf(-x));
}

// ---------------- Wm f32 -> bf16 ----------------
__global__ void conv_bf16(const float4* __restrict__ src, ushort4* __restrict__ dst, int n4){
  int i = blockIdx.x*256 + threadIdx.x;
  if (i < n4) dst[i] = f2bf4(src[i]);
}

// ---------------- small f32 GEMM with K-split atomics ----------------
// out[b][n] += sum_k A[b][k] * W[n][k]   (M=128 fixed)
// mode 0: A=[x|op|hp] K=1280, W=[Wih|Whh], N=2048
// mode 1: A=hn K=512, W=Wq, N=512
// mode 2: A=[hn|ctx] K=1024, W=Wo, N=512
__device__ __forceinline__ const float* fetch_in(int mode, const float* a0, const float* a1,
                                                 const float* a2, int b, int k){
  if (mode == 0){
    if (k < 256)  return a0 + b*256 + k;
    if (k < 768)  return a1 + b*512 + (k-256);
    return a2 + b*512 + (k-768);
  }
  if (mode == 1) return a0 + b*512 + k;
  if (k < 512)   return a0 + b*512 + k;
  return a1 + b*512 + (k-512);
}
__device__ __forceinline__ const float* fetch_w(int mode, const float* w0, const float* w1,
                                                int n, int k){
  if (mode == 0){
    if (k < 768) return w0 + (size_t)n*768 + k;
    return w1 + (size_t)n*512 + (k-768);
  }
  if (mode == 1) return w0 + (size_t)n*512 + k;
  return w0 + (size_t)n*1024 + k;
}

__global__ void sgemm_acc(int mode,
    const float* __restrict__ a0, const float* __restrict__ a1, const float* __restrict__ a2,
    const float* __restrict__ w0, const float* __restrict__ w1,
    float* __restrict__ out, int N, int kchunk)
{
  __shared__ float inp_s[64*132];   // [k][b], pad 128->132
  __shared__ float w_s[64*40];      // [k][n], pad 32->40
  int tid = threadIdx.x;
  int nt = blockIdx.x, kid = blockIdx.y;
  int bg = tid & 31, ng = tid >> 5;           // compute tile: 4b x 4n
  int sb = tid >> 1, skof = (tid & 1)*32;     // input staging
  int wn = tid & 31, wkg = tid >> 5;          // weight staging
  float acc[4][4] = {};
  int substeps = kchunk >> 6;

  for (int s = 0; s < substeps; ++s){
    int ks = kid*kchunk + s*64;
    __syncthreads();
    { // stage inputs: 128 b x 64 k
      const float* src = fetch_in(mode, a0, a1, a2, sb, ks + skof);
      #pragma unroll
      for (int j8 = 0; j8 < 8; ++j8){
        float4 v = ((const float4*)src)[j8];
        int kk = skof + j8*4;
        inp_s[(kk+0)*132 + sb] = v.x;
        inp_s[(kk+1)*132 + sb] = v.y;
        inp_s[(kk+2)*132 + sb] = v.z;
        inp_s[(kk+3)*132 + sb] = v.w;
      }
      // stage weights: 32 n x 64 k
      int nglob = nt*32 + wn;
      const float* wsrc = fetch_w(mode, w0, w1, nglob, ks + wkg*8);
      float4 v0 = ((const float4*)wsrc)[0];
      float4 v1 = ((const float4*)wsrc)[1];
      int kk = wkg*8;
      w_s[(kk+0)*40 + wn] = v0.x;  w_s[(kk+1)*40 + wn] = v0.y;
      w_s[(kk+2)*40 + wn] = v0.z;  w_s[(kk+3)*40 + wn] = v0.w;
      w_s[(kk+4)*40 + wn] = v1.x;  w_s[(kk+5)*40 + wn] = v1.y;
      w_s[(kk+6)*40 + wn] = v1.z;  w_s[(kk+7)*40 + wn] = v1.w;
    }
    __syncthreads();
    #pragma unroll 4
    for (int k = 0; k < 64; ++k){
      float4v vb = *(const float4v*)&inp_s[k*132 + bg*4];
      float4v vw = *(const float4v*)&w_s[k*40 + ng*4];
      #pragma unroll
      for (int i = 0; i < 4; ++i)
        #pragma unroll
        for (int j = 0; j < 4; ++j)
          acc[i][j] = fmaf(vb[i], vw[j], acc[i][j]);
    }
  }
  #pragma unroll
  for (int i = 0; i < 4; ++i)
    #pragma unroll
    for (int j = 0; j < 4; ++j)
      atomicAdd(&out[(size_t)(bg*4+i)*N + nt*32 + ng*4 + j], acc[i][j]);
}

// ---------------- LSTM activations ----------------
__global__ void lstm_act(const float* __restrict__ gates,
    const float* __restrict__ bih, const float* __restrict__ bhh,
    const float* __restrict__ cp, float* __restrict__ hn_out, float* __restrict__ cn_out)
{
  int i = blockIdx.x*256 + threadIdx.x;   // 65536
  int b = i >> 9, h = i & 511;
  const float* g = gates + (size_t)b*2048;
  float g0 = g[h]      + bih[h]      + bhh[h];
  float g1 = g[512+h]  + bih[512+h]  + bhh[512+h];
  float g2 = g[1024+h] + bih[1024+h] + bhh[1024+h];
  float g3 = g[1536+h] + bih[1536+h] + bhh[1536+h];
  float ig = fast_sig(g0), fg = fast_sig(g1);
  float gg = fast_tanh(g2), og = fast_sig(g3);
  float cv = fg*cp[i] + ig*gg;
  float hv = og*fast_tanh(cv);
  cn_out[i] = cv;
  hn_out[i] = hv;
}

// ---------------- attention k-GEMM + tanh·wa partial-score reduction ----------------
// grid 4096, XCD-pinned decode (see R4): nc-siblings co-locate on one XCD.
// block 256 (4 waves, 2M x 2N), block tile 128t x 128n, K=512 in 16 steps of 32.
// LDS exactly 32 KB (sred overlaid on As after the K-loop) -> 5 blocks/CU, 20 waves.
__global__ __launch_bounds__(256, 5) void attn_gemm(
    const float* __restrict__ enc, const unsigned short* __restrict__ wmbf,
    const float* __restrict__ q, const float* __restrict__ wa,
    float* __restrict__ sp)
{
  __shared__ unsigned short As[2][4096];   // 128r x 32k bf16, swizzled
  __shared__ unsigned short Bs[2][4096];

  int tid = threadIdx.x;
  int blk = blockIdx.x;
  // XCD-pinned decode (bijective over 4096): tile = xcd + 8*(slot>>2), nc = slot&3
  int xcd = blk & 7, slot = blk >> 3;
  int tile = xcd + 8*(slot >> 2);
  int nc = slot & 3;
  int b = tile >> 3, tc = tile & 7;
  int tbase = tc*128, n0 = nc*128;
  int w = tid >> 6, lane = tid & 63;
  int wm = w >> 1, wn = w & 1;
  int c = lane & 15, q4 = lane >> 4;

  float4v acc[4][4];
  #pragma unroll
  for (int i = 0; i < 4; ++i)
    #pragma unroll
    for (int j = 0; j < 4; ++j) acc[i][j] = (float4v)0.f;

  // staging: thread -> row sr (0..127), k-half sh (16 elems)
  int sr = tid >> 1, sh = tid & 1;
  const float* asrc = enc + ((size_t)(b*1024 + tbase + sr))*512 + sh*16;
  const unsigned short* bsrc = wmbf + (size_t)(n0 + sr)*512 + sh*16;
  // swizzled write offsets (ushort units) for the two 16B chunks this thread stages
  int srp = sr >> 1, sodd = sr & 1;
  int wo0 = srp*64 + ((sodd*4 + sh*2    ) ^ (srp & 7))*8;
  int wo1 = srp*64 + ((sodd*4 + sh*2 + 1) ^ (srp & 7))*8;

  // swizzled fragment read offsets (ushort units)
  int a_off[4], b_off[4];
  #pragma unroll
  for (int mi = 0; mi < 4; ++mi){
    int r = wm*64 + mi*16 + c;
    a_off[mi] = (r >> 1)*64 + (((r & 1)*4 + q4) ^ ((r >> 1) & 7))*8;
  }
  #pragma unroll
  for (int ni = 0; ni < 4; ++ni){
    int r = wn*64 + ni*16 + c;
    b_off[ni] = (r >> 1)*64 + (((r & 1)*4 + q4) ^ ((r >> 1) & 7))*8;
  }

  float4 a0, a1, a2, a3;
  uint4 bv0, bv1;

  // prologue: load ks=0
  a0 = ((const float4*)asrc)[0]; a1 = ((const float4*)asrc)[1];
  a2 = ((const float4*)asrc)[2]; a3 = ((const float4*)asrc)[3];
  bv0 = *(const uint4*)(bsrc);   bv1 = *(const uint4*)(bsrc + 8);
  // write buf 0
  {
    uint4 ca, cb;
    ca.x = cvt_pk_bf16(a0.x, a0.y); ca.y = cvt_pk_bf16(a0.z, a0.w);
    ca.z = cvt_pk_bf16(a1.x, a1.y); ca.w = cvt_pk_bf16(a1.z, a1.w);
    cb.x = cvt_pk_bf16(a2.x, a2.y); cb.y = cvt_pk_bf16(a2.z, a2.w);
    cb.z = cvt_pk_bf16(a3.x, a3.y); cb.w = cvt_pk_bf16(a3.z, a3.w);
    *(uint4*)&As[0][wo0] = ca; *(uint4*)&As[0][wo1] = cb;
    *(uint4*)&Bs[0][wo0] = bv0; *(uint4*)&Bs[0][wo1] = bv1;
  }
  // load ks=1
  a0 = ((const float4*)(asrc + 32))[0]; a1 = ((const float4*)(asrc + 32))[1];
  a2 = ((const float4*)(asrc + 32))[2]; a3 = ((const float4*)(asrc + 32))[3];
  bv0 = *(const uint4*)(bsrc + 32);     bv1 = *(const uint4*)(bsrc + 40);
  __syncthreads();

  for (int ks = 0; ks < 16; ++ks){
    int cur = ks & 1;
    if (ks < 15){
      // write prefetched (ks+1) -> other buffer
      uint4 ca, cb;
      ca.x = cvt_pk_bf16(a0.x, a0.y); ca.y = cvt_pk_bf16(a0.z, a0.w);
      ca.z = cvt_pk_bf16(a1.x, a1.y); ca.w = cvt_pk_bf16(a1.z, a1.w);
      cb.x = cvt_pk_bf16(a2.x, a2.y); cb.y = cvt_pk_bf16(a2.z, a2.w);
      cb.z = cvt_pk_bf16(a3.x, a3.y); cb.w = cvt_pk_bf16(a3.z, a3.w);
      *(uint4*)&As[cur^1][wo0] = ca; *(uint4*)&As[cur^1][wo1] = cb;
      *(uint4*)&Bs[cur^1][wo0] = bv0; *(uint4*)&Bs[cur^1][wo1] = bv1;
      if (ks < 14){
        int k0 = (ks + 2)*32;
        a0 = ((const float4*)(asrc + k0))[0]; a1 = ((const float4*)(asrc + k0))[1];
        a2 = ((const float4*)(asrc + k0))[2]; a3 = ((const float4*)(asrc + k0))[3];
        bv0 = *(const uint4*)(bsrc + k0);     bv1 = *(const uint4*)(bsrc + k0 + 8);
      }
    }
    short8 af[4];
    #pragma unroll
    for (int mi = 0; mi < 4; ++mi)
      af[mi] = *(const short8*)&As[cur][a_off[mi]];
    #pragma unroll
    for (int ni = 0; ni < 4; ++ni){
      short8 bf = *(const short8*)&Bs[cur][b_off[ni]];
      #pragma unroll
      for (int mi = 0; mi < 4; ++mi)
        acc[mi][ni] = __builtin_amdgcn_mfma_f32_16x16x32_bf16(af[mi], bf, acc[mi][ni], 0, 0, 0);
    }
    __syncthreads();
  }

  // epilogue: s[t] partial = sum_{n in tile} wa[n]*tanh(q[n] + k[t,n])
  // sred overlaid onto As (dead after final barrier) -> LDS stays 32 KB
  float* sred = (float*)&As[0][0];   // [2][128]
  float qv[4], wv[4];
  #pragma unroll
  for (int ni = 0; ni < 4; ++ni){
    int n = n0 + wn*64 + ni*16 + c;
    qv[ni] = q[b*512 + n]; wv[ni] = wa[n];
  }
  #pragma unroll
  for (int mi = 0; mi < 4; ++mi){
    #pragma unroll
    for (int r = 0; r < 4; ++r){
      float v = 0.f;
      #pragma unroll
      for (int ni = 0; ni < 4; ++ni)
        v += wv[ni] * fast_tanh(qv[ni] + acc[mi][ni][r]);
      v += __shfl_xor(v, 1); v += __shfl_xor(v, 2);
      v += __shfl_xor(v, 4); v += __shfl_xor(v, 8);
      if (c == 0) sred[wn*128 + wm*64 + mi*16 + q4*4 + r] = v;
    }
  }
  __syncthreads();
  if (tid < 128)
    sp[nc*131072 + b*1024 + tbase + tid] = sred[tid] + sred[128 + tid];
}

// ---------------- fused softmax + context partial ----------------
// grid 1024 = (b=128) x (tc=8), block 512. Each block recomputes the full row
// softmax from sp (cheap: 16 KB), writes its out_w slice, then accumulates its
// ctx partial with coalesced enc reads + atomicAdd.
__global__ __launch_bounds__(512) void attn_sm_ctx(const float* __restrict__ sp,
    const float* __restrict__ enc, float* __restrict__ wf, float* __restrict__ ctx)
{
  __shared__ float sv[1024];
  __shared__ float red[8], red2[8];
  int blk = blockIdx.x;
  int b = blk >> 3, tc = blk & 7;
  int tid = threadIdx.x;
  int w = tid >> 6, lane = tid & 63;
  int t1 = tid + 512;
  float s0 = sp[b*1024 + tid] + sp[131072 + b*1024 + tid]
           + sp[262144 + b*1024 + tid] + sp[393216 + b*1024 + tid];
  float s1 = sp[b*1024 + t1] + sp[131072 + b*1024 + t1]
           + sp[262144 + b*1024 + t1] + sp[393216 + b*1024 + t1];
  float m = fmaxf(s0, s1);
  m = fmaxf(m, __shfl_xor(m, 32)); m = fmaxf(m, __shfl_xor(m, 16));
  m = fmaxf(m, __shfl_xor(m, 8));  m = fmaxf(m, __shfl_xor(m, 4));
  m = fmaxf(m, __shfl_xor(m, 2));  m = fmaxf(m, __shfl_xor(m, 1));
  if (lane == 0) red[w] = m;
  __syncthreads();
  float M = red[0];
  #pragma unroll
  for (int i = 1; i < 8; ++i) M = fmaxf(M, red[i]);
  float p0 = __expf(s0 - M), p1 = __expf(s1 - M);
  float t = p0 + p1;
  t += __shfl_xor(t, 32); t += __shfl_xor(t, 16); t += __shfl_xor(t, 8);
  t += __shfl_xor(t, 4);  t += __shfl_xor(t, 2);  t += __shfl_xor(t, 1);
  if (lane == 0) red2[w] = t;
  __syncthreads();
  float L = 0.f;
  #pragma unroll
  for (int i = 0; i < 8; ++i) L += red2[i];
  float invL = __fdividef(1.f, L);
  sv[tid] = p0*invL;
  sv[t1]  = p1*invL;
  __syncthreads();
  int tbase = tc*128;
  if (tid < 128) wf[b*1024 + tbase + tid] = sv[tbase + tid];
  const float* ep = enc + ((size_t)(b*1024 + tbase))*512 + tid;
  float a = 0.f;
  #pragma unroll 8
  for (int t2 = 0; t2 < 128; ++t2)
    a = fmaf(sv[tbase + t2], ep[(size_t)t2*512], a);
  atomicAdd(&ctx[b*512 + tid], a);
}

// ---------------- tanh activation (on), also emits bf16 copy for head_gemm ----------------
__global__ void tanh_act(const float* __restrict__ in, float* __restrict__ out,
                         unsigned short* __restrict__ outbf){
  int i = blockIdx.x*256 + threadIdx.x;   // 65536
  float v = fast_tanh(in[i]);
  out[i] = v;
  outbf[i] = f2bf(v);
}

// ---------------- head GEMM: logits = on @ Wout^T (bf16 MFMA) ----------------
// grid 500 (= 32000/64), block 256 (4 waves, 2M x 2N), WG tile 128 x 64, K=512.
// ~2 blocks/CU. A pre-converted bf16 (onbf); B converted in staging.
// dbuf LDS (swizzled, conflict-free), 2-step register prefetch, 1 barrier/step.
__global__ __launch_bounds__(256) void head_gemm(const unsigned short* __restrict__ onbf,
    const float* __restrict__ wout, float* __restrict__ outp)
{
  __shared__ unsigned short As[2][4096];   // 128r x 32k
  __shared__ unsigned short Bs[2][2048];   // 64r x 32k
  int tid = threadIdx.x;
  int n0 = blockIdx.x * 64;
  int w = tid >> 6, lane = tid & 63;
  int wm = w >> 1, wn = w & 1;
  int c = lane & 15, q4 = lane >> 4;

  float4v acc[4][2];
  #pragma unroll
  for (int i = 0; i < 4; ++i)
    #pragma unroll
    for (int j = 0; j < 2; ++j) acc[i][j] = (float4v)0.f;

  // A staging: row sr (0..127), half sh -> 2 x uint4 (16 bf16) per step
  int sr = tid >> 1, sh = tid & 1;
  const unsigned short* asrc = onbf + (size_t)sr*512 + sh*16;
  int srp = sr >> 1, sodd = sr & 1;
  int awo0 = srp*64 + ((sodd*4 + sh*2    ) ^ (srp & 7))*8;
  int awo1 = srp*64 + ((sodd*4 + sh*2 + 1) ^ (srp & 7))*8;
  // B staging: row rb (0..63), chunk jb (0..3) of 8 f32 -> 1 uint4 bf16 per step
  int rb = tid >> 2, jb = tid & 3;
  const float* bsrc = wout + (size_t)(n0 + rb)*512 + jb*8;
  int rbp = rb >> 1, rbo = rb & 1;
  int bwo = rbp*64 + ((rbo*4 + jb) ^ (rbp & 7))*8;

  int a_off[4], b_off[2];
  #pragma unroll
  for (int mi = 0; mi < 4; ++mi){
    int r = wm*64 + mi*16 + c;
    a_off[mi] = (r >> 1)*64 + (((r & 1)*4 + q4) ^ ((r >> 1) & 7))*8;
  }
  #pragma unroll
  for (int ni = 0; ni < 2; ++ni){
    int r = wn*32 + ni*16 + c;
    b_off[ni] = (r >> 1)*64 + (((r & 1)*4 + q4) ^ ((r >> 1) & 7))*8;
  }

  uint4 pa0, pa1;
  float4 pb0, pb1;
  // prologue: load ks=0
  pa0 = ((const uint4*)asrc)[0]; pa1 = ((const uint4*)asrc)[1];
  pb0 = ((const float4*)bsrc)[0]; pb1 = ((const float4*)bsrc)[1];
  {
    *(uint4*)&As[0][awo0] = pa0; *(uint4*)&As[0][awo1] = pa1;
    uint4 cb;
    cb.x = cvt_pk_bf16(pb0.x, pb0.y); cb.y = cvt_pk_bf16(pb0.z, pb0.w);
    cb.z = cvt_pk_bf16(pb1.x, pb1.y); cb.w = cvt_pk_bf16(pb1.z, pb1.w);
    *(uint4*)&Bs[0][bwo] = cb;
  }
  // load ks=1
  pa0 = ((const uint4*)(asrc + 32))[0]; pa1 = ((const uint4*)(asrc + 32))[1];
  pb0 = ((const float4*)(bsrc + 32))[0]; pb1 = ((const float4*)(bsrc + 32))[1];
  __syncthreads();

  for (int ks = 0; ks < 16; ++ks){
    int cur = ks & 1;
    if (ks < 15){
      *(uint4*)&As[cur^1][awo0] = pa0; *(uint4*)&As[cur^1][awo1] = pa1;
      uint4 cb;
      cb.x = cvt_pk_bf16(pb0.x, pb0.y); cb.y = cvt_pk_bf16(pb0.z, pb0.w);
      cb.z = cvt_pk_bf16(pb1.x, pb1.y); cb.w = cvt_pk_bf16(pb1.z, pb1.w);
      *(uint4*)&Bs[cur^1][bwo] = cb;
      if (ks < 14){
        int k0 = (ks + 2)*32;
        pa0 = ((const uint4*)(asrc + k0))[0]; pa1 = ((const uint4*)(asrc + k0))[1];
        pb0 = ((const float4*)(bsrc + k0))[0]; pb1 = ((const float4*)(bsrc + k0))[1];
      }
    }
    short8 af[4];
    #pragma unroll
    for (int mi = 0; mi < 4; ++mi)
      af[mi] = *(const short8*)&As[cur][a_off[mi]];
    #pragma unroll
    for (int ni = 0; ni < 2; ++ni){
      short8 bf = *(const short8*)&Bs[cur][b_off[ni]];
      #pragma unroll
      for (int mi = 0; mi < 4; ++mi)
        acc[mi][ni] = __builtin_amdgcn_mfma_f32_16x16x32_bf16(af[mi], bf, acc[mi][ni], 0, 0, 0);
    }
    __syncthreads();
  }
  #pragma unroll
  for (int mi = 0; mi < 4; ++mi)
    #pragma unroll
    for (int ni = 0; ni < 2; ++ni)
      #pragma unroll
      for (int r = 0; r < 4; ++r){
        int m = wm*64 + mi*16 + q4*4 + r;
        int n = n0 + wn*32 + ni*16 + c;
        outp[(size_t)m*32000 + n] = acc[mi][ni][r];
      }
}

// ---------------- fused per-row logsumexp + in-place subtract ----------------
__global__ __launch_bounds__(1024) void lse_fused(float* __restrict__ outp){
  __shared__ float rm[16], rs[16];
  int b = blockIdx.x, tid = threadIdx.x;
  int w = tid >> 6, lane = tid & 63;
  float* row = outp + (size_t)b*32000;
  float m = -1e30f, s = 0.f;
  for (int v = tid; v < 32000; v += 1024){
    float x = row[v];
    if (x > m){ s = s*__expf(m - x) + 1.f; m = x; }
    else s += __expf(x - m);
  }
  for (int off = 32; off; off >>= 1){
    float mo = __shfl_xor(m, off), so = __shfl_xor(s, off);
    float M2 = fmaxf(m, mo);
    s = s*__expf(m - M2) + so*__expf(mo - M2);
    m = M2;
  }
  if (lane == 0){ rm[w] = m; rs[w] = s; }
  __syncthreads();
  float M = rm[0];
  #pragma unroll
  for (int i = 1; i < 16; ++i) M = fmaxf(M, rm[i]);
  float S = 0.f;
  #pragma unroll
  for (int i = 0; i < 16; ++i) S += rs[i]*__expf(rm[i] - M);
  float l = M + __logf(S);
  for (int v = tid; v < 32000; v += 1024)
    row[v] -= l;
}

extern "C" void kernel_launch(void* const* d_in, const int* in_sizes, int n_in,
                              void* d_out, int out_size, void* d_ws, size_t ws_size,
                              hipStream_t stream)
{
  (void)in_sizes; (void)n_in; (void)out_size; (void)ws_size;
  const float* x    = (const float*)d_in[0];
  const float* hp   = (const float*)d_in[1];
  const float* cp   = (const float*)d_in[2];
  const float* op   = (const float*)d_in[3];
  const float* enc  = (const float*)d_in[4];
  const float* Wih  = (const float*)d_in[5];
  const float* Whh  = (const float*)d_in[6];
  const float* bih  = (const float*)d_in[7];
  const float* bhh  = (const float*)d_in[8];
  const float* Wq   = (const float*)d_in[9];
  const float* Wm   = (const float*)d_in[10];
  const float* Wa   = (const float*)d_in[11];
  const float* Wo   = (const float*)d_in[12];
  const float* Wout = (const float*)d_in[13];
  float* out = (float*)d_out;

  float* ws = (float*)d_ws;
  float* gates   = ws + 0;                               // 262144
  float* qbuf    = ws + 262144;                          // 65536
  unsigned short* wmbf = (unsigned short*)(ws + 327680); // 262144 bf16 (131072 f32 slots)
  float* spb     = ws + 458752;                          // 524288 = [4][128*1024]
  float* ctxb    = ws + 983040;                          // 65536
  float* oaccb   = ws + 1048576;                         // 65536
  unsigned short* onbf = (unsigned short*)(ws + 1114112);// 65536 bf16 (32768 f32 slots)

  float* out_logits = out;                 // 4,096,000
  float* out_hn = out + 4096000;           // 65,536
  float* out_cn = out + 4161536;           // 65,536
  float* out_on = out + 4227072;           // 65,536
  float* out_w  = out + 4292608;           // 131,072

  hipMemsetAsync(gates, 0, (size_t)(262144 + 65536)*sizeof(float), stream); // gates + q
  hipMemsetAsync(ctxb, 0, (size_t)(65536 + 65536)*sizeof(float), stream);   // ctx + oacc

  conv_bf16<<<256, 256, 0, stream>>>((const float4*)Wm, (ushort4*)wmbf, 65536);
  sgemm_acc<<<dim3(64, 4), 256, 0, stream>>>(0, x, op, hp, Wih, Whh, gates, 2048, 320);
  lstm_act<<<256, 256, 0, stream>>>(gates, bih, bhh, cp, out_hn, out_cn);
  sgemm_acc<<<dim3(16, 8), 256, 0, stream>>>(1, out_hn, nullptr, nullptr, Wq, nullptr, qbuf, 512, 64);
  attn_gemm<<<4096, 256, 0, stream>>>(enc, wmbf, qbuf, Wa, spb);
  attn_sm_ctx<<<1024, 512, 0, stream>>>(spb, enc, out_w, ctxb);
  sgemm_acc<<<dim3(16, 8), 256, 0, stream>>>(2, out_hn, ctxb, nullptr, Wo, nullptr, oaccb, 512, 128);
  tanh_act<<<256, 256, 0, stream>>>(oaccb, out_on, onbf);
  head_gemm<<<500, 256, 0, stream>>>(onbf, Wout, out_logits);
  lse_fused<<<128, 1024, 0, stream>>>(out_logits);
}

// Round 6
// 720.493 us; speedup vs baseline: 1.0519x; 1.0519x over previous
//
#include <hip/hip_runtime.h>

// Problem dims
#define B_ 128
#define T_ 1024
#define I_ 256
#define H_ 512
#define V_ 32000

typedef float  float4v __attribute__((ext_vector_type(4)));
typedef short  short8  __attribute__((ext_vector_type(8)));

__device__ __forceinline__ unsigned short f2bf(float f){
  unsigned int u = __float_as_uint(f);
  u += 0x7fffu + ((u >> 16) & 1u);          // round-to-nearest-even
  return (unsigned short)(u >> 16);
}
__device__ __forceinline__ unsigned int cvt_pk_bf16(float lo, float hi){
  unsigned int r;
  asm volatile("v_cvt_pk_bf16_f32 %0, %1, %2" : "=v"(r) : "v"(lo), "v"(hi));
  return r;
}
__device__ __forceinline__ float fast_tanh(float x){
  float e = __expf(2.f*x);
  return 1.f - __fdividef(2.f, e + 1.f);
}
__device__ __forceinline__ float fast_sig(float x){
  return __fdividef(1.f, 1.f + __expf(-x));
}

// ---------------- small f32 GEMM with K-split atomics ----------------
// out[b][n] += sum_k A[b][k] * W[n][k]   (M=128 fixed)
// mode 0: A=[x|op|hp] K=1280, W=[Wih|Whh], N=2048
// mode 1: A=hn K=512, W=Wq, N=512
// mode 2: A=[hn|ctx] K=1024, W=Wo, N=512
__device__ __forceinline__ const float* fetch_in(int mode, const float* a0, const float* a1,
                                                 const float* a2, int b, int k){
  if (mode == 0){
    if (k < 256)  return a0 + b*256 + k;
    if (k < 768)  return a1 + b*512 + (k-256);
    return a2 + b*512 + (k-768);
  }
  if (mode == 1) return a0 + b*512 + k;
  if (k < 512)   return a0 + b*512 + k;
  return a1 + b*512 + (k-512);
}
__device__ __forceinline__ const float* fetch_w(int mode, const float* w0, const float* w1,
                                                int n, int k){
  if (mode == 0){
    if (k < 768) return w0 + (size_t)n*768 + k;
    return w1 + (size_t)n*512 + (k-768);
  }
  if (mode == 1) return w0 + (size_t)n*512 + k;
  return w0 + (size_t)n*1024 + k;
}

__global__ void sgemm_acc(int mode,
    const float* __restrict__ a0, const float* __restrict__ a1, const float* __restrict__ a2,
    const float* __restrict__ w0, const float* __restrict__ w1,
    float* __restrict__ out, int N, int kchunk)
{
  __shared__ float inp_s[64*132];   // [k][b], pad 128->132
  __shared__ float w_s[64*40];      // [k][n], pad 32->40
  int tid = threadIdx.x;
  int nt = blockIdx.x, kid = blockIdx.y;
  int bg = tid & 31, ng = tid >> 5;           // compute tile: 4b x 4n
  int sb = tid >> 1, skof = (tid & 1)*32;     // input staging
  int wn = tid & 31, wkg = tid >> 5;          // weight staging
  float acc[4][4] = {};
  int substeps = kchunk >> 6;

  for (int s = 0; s < substeps; ++s){
    int ks = kid*kchunk + s*64;
    __syncthreads();
    { // stage inputs: 128 b x 64 k
      const float* src = fetch_in(mode, a0, a1, a2, sb, ks + skof);
      #pragma unroll
      for (int j8 = 0; j8 < 8; ++j8){
        float4 v = ((const float4*)src)[j8];
        int kk = skof + j8*4;
        inp_s[(kk+0)*132 + sb] = v.x;
        inp_s[(kk+1)*132 + sb] = v.y;
        inp_s[(kk+2)*132 + sb] = v.z;
        inp_s[(kk+3)*132 + sb] = v.w;
      }
      // stage weights: 32 n x 64 k
      int nglob = nt*32 + wn;
      const float* wsrc = fetch_w(mode, w0, w1, nglob, ks + wkg*8);
      float4 v0 = ((const float4*)wsrc)[0];
      float4 v1 = ((const float4*)wsrc)[1];
      int kk = wkg*8;
      w_s[(kk+0)*40 + wn] = v0.x;  w_s[(kk+1)*40 + wn] = v0.y;
      w_s[(kk+2)*40 + wn] = v0.z;  w_s[(kk+3)*40 + wn] = v0.w;
      w_s[(kk+4)*40 + wn] = v1.x;  w_s[(kk+5)*40 + wn] = v1.y;
      w_s[(kk+6)*40 + wn] = v1.z;  w_s[(kk+7)*40 + wn] = v1.w;
    }
    __syncthreads();
    #pragma unroll 4
    for (int k = 0; k < 64; ++k){
      float4v vb = *(const float4v*)&inp_s[k*132 + bg*4];
      float4v vw = *(const float4v*)&w_s[k*40 + ng*4];
      #pragma unroll
      for (int i = 0; i < 4; ++i)
        #pragma unroll
        for (int j = 0; j < 4; ++j)
          acc[i][j] = fmaf(vb[i], vw[j], acc[i][j]);
    }
  }
  #pragma unroll
  for (int i = 0; i < 4; ++i)
    #pragma unroll
    for (int j = 0; j < 4; ++j)
      atomicAdd(&out[(size_t)(bg*4+i)*N + nt*32 + ng*4 + j], acc[i][j]);
}

// ---------------- LSTM activations ----------------
__global__ void lstm_act(const float* __restrict__ gates,
    const float* __restrict__ bih, const float* __restrict__ bhh,
    const float* __restrict__ cp, float* __restrict__ hn_out, float* __restrict__ cn_out)
{
  int i = blockIdx.x*256 + threadIdx.x;   // 65536
  int b = i >> 9, h = i & 511;
  const float* g = gates + (size_t)b*2048;
  float g0 = g[h]      + bih[h]      + bhh[h];
  float g1 = g[512+h]  + bih[512+h]  + bhh[512+h];
  float g2 = g[1024+h] + bih[1024+h] + bhh[1024+h];
  float g3 = g[1536+h] + bih[1536+h] + bhh[1536+h];
  float ig = fast_sig(g0), fg = fast_sig(g1);
  float gg = fast_tanh(g2), og = fast_sig(g3);
  float cv = fg*cp[i] + ig*gg;
  float hv = og*fast_tanh(cv);
  cn_out[i] = cv;
  hn_out[i] = hv;
}

// ---------------- attention k-GEMM + tanh·wa partial-score reduction ----------------
// grid 4096, XCD-pinned decode: nc-siblings co-locate on one XCD (R4: FETCH 528->137MB).
// block 256 (4 waves, 2M x 2N), block tile 128t x 128n, K=512 in 16 steps of 32.
// LDS exactly 32 KB (sred overlaid on As after the K-loop).
// launch_bounds(256,4): do NOT raise to 5 — R5 showed the allocator then caps at
// 48 VGPR and spills the 64-reg accumulator to scratch (WRITE_SIZE 6->98 MB, +58us).
// Wm is consumed as f32 and converted in B-staging (conv_bf16 dispatch eliminated;
// Wm is 1 MB -> L2/L3-resident across all 1024 consumers per column chunk).
__global__ __launch_bounds__(256, 4) void attn_gemm(
    const float* __restrict__ enc, const float* __restrict__ wm,
    const float* __restrict__ q, const float* __restrict__ wa,
    float* __restrict__ sp)
{
  __shared__ unsigned short As[2][4096];   // 128r x 32k bf16, swizzled
  __shared__ unsigned short Bs[2][4096];

  int tid = threadIdx.x;
  int blk = blockIdx.x;
  // XCD-pinned decode (bijective over 4096): tile = xcd + 8*(slot>>2), nc = slot&3
  int xcd = blk & 7, slot = blk >> 3;
  int tile = xcd + 8*(slot >> 2);
  int nc = slot & 3;
  int b = tile >> 3, tc = tile & 7;
  int tbase = tc*128, n0 = nc*128;
  int w = tid >> 6, lane = tid & 63;
  int wm_ = w >> 1, wn = w & 1;
  int c = lane & 15, q4 = lane >> 4;

  float4v acc[4][4];
  #pragma unroll
  for (int i = 0; i < 4; ++i)
    #pragma unroll
    for (int j = 0; j < 4; ++j) acc[i][j] = (float4v)0.f;

  // staging: thread -> row sr (0..127), k-half sh (16 elems)
  int sr = tid >> 1, sh = tid & 1;
  const float* asrc = enc + ((size_t)(b*1024 + tbase + sr))*512 + sh*16;
  const float* bsrc = wm + (size_t)(n0 + sr)*512 + sh*16;
  // swizzled write offsets (ushort units) for the two 16B chunks this thread stages
  int srp = sr >> 1, sodd = sr & 1;
  int wo0 = srp*64 + ((sodd*4 + sh*2    ) ^ (srp & 7))*8;
  int wo1 = srp*64 + ((sodd*4 + sh*2 + 1) ^ (srp & 7))*8;

  // swizzled fragment read offsets (ushort units)
  int a_off[4], b_off[4];
  #pragma unroll
  for (int mi = 0; mi < 4; ++mi){
    int r = wm_*64 + mi*16 + c;
    a_off[mi] = (r >> 1)*64 + (((r & 1)*4 + q4) ^ ((r >> 1) & 7))*8;
  }
  #pragma unroll
  for (int ni = 0; ni < 4; ++ni){
    int r = wn*64 + ni*16 + c;
    b_off[ni] = (r >> 1)*64 + (((r & 1)*4 + q4) ^ ((r >> 1) & 7))*8;
  }

  float4 a0, a1, a2, a3, b0, b1, b2, b3;

  // prologue: load ks=0
  a0 = ((const float4*)asrc)[0]; a1 = ((const float4*)asrc)[1];
  a2 = ((const float4*)asrc)[2]; a3 = ((const float4*)asrc)[3];
  b0 = ((const float4*)bsrc)[0]; b1 = ((const float4*)bsrc)[1];
  b2 = ((const float4*)bsrc)[2]; b3 = ((const float4*)bsrc)[3];
  // write buf 0
  {
    uint4 ca, cb, cc, cd;
    ca.x = cvt_pk_bf16(a0.x, a0.y); ca.y = cvt_pk_bf16(a0.z, a0.w);
    ca.z = cvt_pk_bf16(a1.x, a1.y); ca.w = cvt_pk_bf16(a1.z, a1.w);
    cb.x = cvt_pk_bf16(a2.x, a2.y); cb.y = cvt_pk_bf16(a2.z, a2.w);
    cb.z = cvt_pk_bf16(a3.x, a3.y); cb.w = cvt_pk_bf16(a3.z, a3.w);
    cc.x = cvt_pk_bf16(b0.x, b0.y); cc.y = cvt_pk_bf16(b0.z, b0.w);
    cc.z = cvt_pk_bf16(b1.x, b1.y); cc.w = cvt_pk_bf16(b1.z, b1.w);
    cd.x = cvt_pk_bf16(b2.x, b2.y); cd.y = cvt_pk_bf16(b2.z, b2.w);
    cd.z = cvt_pk_bf16(b3.x, b3.y); cd.w = cvt_pk_bf16(b3.z, b3.w);
    *(uint4*)&As[0][wo0] = ca; *(uint4*)&As[0][wo1] = cb;
    *(uint4*)&Bs[0][wo0] = cc; *(uint4*)&Bs[0][wo1] = cd;
  }
  // load ks=1
  a0 = ((const float4*)(asrc + 32))[0]; a1 = ((const float4*)(asrc + 32))[1];
  a2 = ((const float4*)(asrc + 32))[2]; a3 = ((const float4*)(asrc + 32))[3];
  b0 = ((const float4*)(bsrc + 32))[0]; b1 = ((const float4*)(bsrc + 32))[1];
  b2 = ((const float4*)(bsrc + 32))[2]; b3 = ((const float4*)(bsrc + 32))[3];
  __syncthreads();

  for (int ks = 0; ks < 16; ++ks){
    int cur = ks & 1;
    if (ks < 15){
      // write prefetched (ks+1) -> other buffer
      uint4 ca, cb, cc, cd;
      ca.x = cvt_pk_bf16(a0.x, a0.y); ca.y = cvt_pk_bf16(a0.z, a0.w);
      ca.z = cvt_pk_bf16(a1.x, a1.y); ca.w = cvt_pk_bf16(a1.z, a1.w);
      cb.x = cvt_pk_bf16(a2.x, a2.y); cb.y = cvt_pk_bf16(a2.z, a2.w);
      cb.z = cvt_pk_bf16(a3.x, a3.y); cb.w = cvt_pk_bf16(a3.z, a3.w);
      cc.x = cvt_pk_bf16(b0.x, b0.y); cc.y = cvt_pk_bf16(b0.z, b0.w);
      cc.z = cvt_pk_bf16(b1.x, b1.y); cc.w = cvt_pk_bf16(b1.z, b1.w);
      cd.x = cvt_pk_bf16(b2.x, b2.y); cd.y = cvt_pk_bf16(b2.z, b2.w);
      cd.z = cvt_pk_bf16(b3.x, b3.y); cd.w = cvt_pk_bf16(b3.z, b3.w);
      *(uint4*)&As[cur^1][wo0] = ca; *(uint4*)&As[cur^1][wo1] = cb;
      *(uint4*)&Bs[cur^1][wo0] = cc; *(uint4*)&Bs[cur^1][wo1] = cd;
      if (ks < 14){
        int k0 = (ks + 2)*32;
        a0 = ((const float4*)(asrc + k0))[0]; a1 = ((const float4*)(asrc + k0))[1];
        a2 = ((const float4*)(asrc + k0))[2]; a3 = ((const float4*)(asrc + k0))[3];
        b0 = ((const float4*)(bsrc + k0))[0]; b1 = ((const float4*)(bsrc + k0))[1];
        b2 = ((const float4*)(bsrc + k0))[2]; b3 = ((const float4*)(bsrc + k0))[3];
      }
    }
    short8 af[4];
    #pragma unroll
    for (int mi = 0; mi < 4; ++mi)
      af[mi] = *(const short8*)&As[cur][a_off[mi]];
    #pragma unroll
    for (int ni = 0; ni < 4; ++ni){
      short8 bf = *(const short8*)&Bs[cur][b_off[ni]];
      #pragma unroll
      for (int mi = 0; mi < 4; ++mi)
        acc[mi][ni] = __builtin_amdgcn_mfma_f32_16x16x32_bf16(af[mi], bf, acc[mi][ni], 0, 0, 0);
    }
    __syncthreads();
  }

  // epilogue: s[t] partial = sum_{n in tile} wa[n]*tanh(q[n] + k[t,n])
  // sred overlaid onto As (dead after final barrier) -> LDS stays 32 KB
  float* sred = (float*)&As[0][0];   // [2][128]
  float qv[4], wv[4];
  #pragma unroll
  for (int ni = 0; ni < 4; ++ni){
    int n = n0 + wn*64 + ni*16 + c;
    qv[ni] = q[b*512 + n]; wv[ni] = wa[n];
  }
  #pragma unroll
  for (int mi = 0; mi < 4; ++mi){
    #pragma unroll
    for (int r = 0; r < 4; ++r){
      float v = 0.f;
      #pragma unroll
      for (int ni = 0; ni < 4; ++ni)
        v += wv[ni] * fast_tanh(qv[ni] + acc[mi][ni][r]);
      v += __shfl_xor(v, 1); v += __shfl_xor(v, 2);
      v += __shfl_xor(v, 4); v += __shfl_xor(v, 8);
      if (c == 0) sred[wn*128 + wm_*64 + mi*16 + q4*4 + r] = v;
    }
  }
  __syncthreads();
  if (tid < 128)
    sp[nc*131072 + b*1024 + tbase + tid] = sred[tid] + sred[128 + tid];
}

// ---------------- fused softmax + context partial ----------------
// grid 1024 = (b=128) x (tc=8), block 512. Each block recomputes the full row
// softmax from sp (cheap: 16 KB), writes its out_w slice, then accumulates its
// ctx partial with coalesced enc reads + atomicAdd.
__global__ __launch_bounds__(512) void attn_sm_ctx(const float* __restrict__ sp,
    const float* __restrict__ enc, float* __restrict__ wf, float* __restrict__ ctx)
{
  __shared__ float sv[1024];
  __shared__ float red[8], red2[8];
  int blk = blockIdx.x;
  int b = blk >> 3, tc = blk & 7;
  int tid = threadIdx.x;
  int w = tid >> 6, lane = tid & 63;
  int t1 = tid + 512;
  float s0 = sp[b*1024 + tid] + sp[131072 + b*1024 + tid]
           + sp[262144 + b*1024 + tid] + sp[393216 + b*1024 + tid];
  float s1 = sp[b*1024 + t1] + sp[131072 + b*1024 + t1]
           + sp[262144 + b*1024 + t1] + sp[393216 + b*1024 + t1];
  float m = fmaxf(s0, s1);
  m = fmaxf(m, __shfl_xor(m, 32)); m = fmaxf(m, __shfl_xor(m, 16));
  m = fmaxf(m, __shfl_xor(m, 8));  m = fmaxf(m, __shfl_xor(m, 4));
  m = fmaxf(m, __shfl_xor(m, 2));  m = fmaxf(m, __shfl_xor(m, 1));
  if (lane == 0) red[w] = m;
  __syncthreads();
  float M = red[0];
  #pragma unroll
  for (int i = 1; i < 8; ++i) M = fmaxf(M, red[i]);
  float p0 = __expf(s0 - M), p1 = __expf(s1 - M);
  float t = p0 + p1;
  t += __shfl_xor(t, 32); t += __shfl_xor(t, 16); t += __shfl_xor(t, 8);
  t += __shfl_xor(t, 4);  t += __shfl_xor(t, 2);  t += __shfl_xor(t, 1);
  if (lane == 0) red2[w] = t;
  __syncthreads();
  float L = 0.f;
  #pragma unroll
  for (int i = 0; i < 8; ++i) L += red2[i];
  float invL = __fdividef(1.f, L);
  sv[tid] = p0*invL;
  sv[t1]  = p1*invL;
  __syncthreads();
  int tbase = tc*128;
  if (tid < 128) wf[b*1024 + tbase + tid] = sv[tbase + tid];
  const float* ep = enc + ((size_t)(b*1024 + tbase))*512 + tid;
  float a = 0.f;
  #pragma unroll 8
  for (int t2 = 0; t2 < 128; ++t2)
    a = fmaf(sv[tbase + t2], ep[(size_t)t2*512], a);
  atomicAdd(&ctx[b*512 + tid], a);
}

// ---------------- tanh activation (on), also emits bf16 copy for head_gemm ----------------
__global__ void tanh_act(const float* __restrict__ in, float* __restrict__ out,
                         unsigned short* __restrict__ outbf){
  int i = blockIdx.x*256 + threadIdx.x;   // 65536
  float v = fast_tanh(in[i]);
  out[i] = v;
  outbf[i] = f2bf(v);
}

// ---------------- head GEMM: logits = on @ Wout^T (bf16 MFMA) ----------------
// grid 1000 (= 32000/32), block 256 (4 waves, 2M x 2N), WG tile 128 x 32, K=512.
// ~4 blocks/CU (vs 2 at the 128x64 tile) -> halves exposed per-step latency.
// A pre-converted bf16 (onbf, L2-hot); B converted in staging (threads < 128).
// dbuf LDS (swizzled, conflict-free), 2-step register prefetch, 1 barrier/step.
__global__ __launch_bounds__(256) void head_gemm(const unsigned short* __restrict__ onbf,
    const float* __restrict__ wout, float* __restrict__ outp)
{
  __shared__ unsigned short As[2][4096];   // 128r x 32k
  __shared__ unsigned short Bs[2][1024];   // 32r x 32k
  int tid = threadIdx.x;
  int n0 = blockIdx.x * 32;
  int w = tid >> 6, lane = tid & 63;
  int wm = w >> 1, wn = w & 1;
  int c = lane & 15, q4 = lane >> 4;

  float4v acc[4];
  #pragma unroll
  for (int i = 0; i < 4; ++i) acc[i] = (float4v)0.f;

  // A staging: row sr (0..127), half sh -> 2 x uint4 (16 bf16) per step
  int sr = tid >> 1, sh = tid & 1;
  const unsigned short* asrc = onbf + (size_t)sr*512 + sh*16;
  int srp = sr >> 1, sodd = sr & 1;
  int awo0 = srp*64 + ((sodd*4 + sh*2    ) ^ (srp & 7))*8;
  int awo1 = srp*64 + ((sodd*4 + sh*2 + 1) ^ (srp & 7))*8;
  // B staging (tid<128 only): row rb (0..31), chunk jb (0..3) of 8 f32 -> 1 uint4
  int rb = (tid >> 2) & 31, jb = tid & 3;
  const float* bsrc = wout + (size_t)(n0 + rb)*512 + jb*8;
  int rbp = rb >> 1, rbo = rb & 1;
  int bwo = rbp*64 + ((rbo*4 + jb) ^ (rbp & 7))*8;
  bool bstage = (tid < 128);

  int a_off[4], b_off;
  #pragma unroll
  for (int mi = 0; mi < 4; ++mi){
    int r = wm*64 + mi*16 + c;
    a_off[mi] = (r >> 1)*64 + (((r & 1)*4 + q4) ^ ((r >> 1) & 7))*8;
  }
  {
    int r = wn*16 + c;
    b_off = (r >> 1)*64 + (((r & 1)*4 + q4) ^ ((r >> 1) & 7))*8;
  }

  uint4 pa0, pa1;
  float4 pb0, pb1;
  // prologue: load ks=0
  pa0 = ((const uint4*)asrc)[0]; pa1 = ((const uint4*)asrc)[1];
  if (bstage){ pb0 = ((const float4*)bsrc)[0]; pb1 = ((const float4*)bsrc)[1]; }
  {
    *(uint4*)&As[0][awo0] = pa0; *(uint4*)&As[0][awo1] = pa1;
    if (bstage){
      uint4 cb;
      cb.x = cvt_pk_bf16(pb0.x, pb0.y); cb.y = cvt_pk_bf16(pb0.z, pb0.w);
      cb.z = cvt_pk_bf16(pb1.x, pb1.y); cb.w = cvt_pk_bf16(pb1.z, pb1.w);
      *(uint4*)&Bs[0][bwo] = cb;
    }
  }
  // load ks=1
  pa0 = ((const uint4*)(asrc + 32))[0]; pa1 = ((const uint4*)(asrc + 32))[1];
  if (bstage){ pb0 = ((const float4*)(bsrc + 32))[0]; pb1 = ((const float4*)(bsrc + 32))[1]; }
  __syncthreads();

  for (int ks = 0; ks < 16; ++ks){
    int cur = ks & 1;
    if (ks < 15){
      *(uint4*)&As[cur^1][awo0] = pa0; *(uint4*)&As[cur^1][awo1] = pa1;
      if (bstage){
        uint4 cb;
        cb.x = cvt_pk_bf16(pb0.x, pb0.y); cb.y = cvt_pk_bf16(pb0.z, pb0.w);
        cb.z = cvt_pk_bf16(pb1.x, pb1.y); cb.w = cvt_pk_bf16(pb1.z, pb1.w);
        *(uint4*)&Bs[cur^1][bwo] = cb;
      }
      if (ks < 14){
        int k0 = (ks + 2)*32;
        pa0 = ((const uint4*)(asrc + k0))[0]; pa1 = ((const uint4*)(asrc + k0))[1];
        if (bstage){ pb0 = ((const float4*)(bsrc + k0))[0]; pb1 = ((const float4*)(bsrc + k0))[1]; }
      }
    }
    short8 bf = *(const short8*)&Bs[cur][b_off];
    #pragma unroll
    for (int mi = 0; mi < 4; ++mi){
      short8 af = *(const short8*)&As[cur][a_off[mi]];
      acc[mi] = __builtin_amdgcn_mfma_f32_16x16x32_bf16(af, bf, acc[mi], 0, 0, 0);
    }
    __syncthreads();
  }
  #pragma unroll
  for (int mi = 0; mi < 4; ++mi)
    #pragma unroll
    for (int r = 0; r < 4; ++r){
      int m = wm*64 + mi*16 + q4*4 + r;
      int n = n0 + wn*16 + c;
      outp[(size_t)m*32000 + n] = acc[mi][r];
    }
}

// ---------------- fused per-row logsumexp + in-place subtract ----------------
__global__ __launch_bounds__(1024) void lse_fused(float* __restrict__ outp){
  __shared__ float rm[16], rs[16];
  int b = blockIdx.x, tid = threadIdx.x;
  int w = tid >> 6, lane = tid & 63;
  float* row = outp + (size_t)b*32000;
  float m = -1e30f, s = 0.f;
  for (int v = tid; v < 32000; v += 1024){
    float x = row[v];
    if (x > m){ s = s*__expf(m - x) + 1.f; m = x; }
    else s += __expf(x - m);
  }
  for (int off = 32; off; off >>= 1){
    float mo = __shfl_xor(m, off), so = __shfl_xor(s, off);
    float M2 = fmaxf(m, mo);
    s = s*__expf(m - M2) + so*__expf(mo - M2);
    m = M2;
  }
  if (lane == 0){ rm[w] = m; rs[w] = s; }
  __syncthreads();
  float M = rm[0];
  #pragma unroll
  for (int i = 1; i < 16; ++i) M = fmaxf(M, rm[i]);
  float S = 0.f;
  #pragma unroll
  for (int i = 0; i < 16; ++i) S += rs[i]*__expf(rm[i] - M);
  float l = M + __logf(S);
  for (int v = tid; v < 32000; v += 1024)
    row[v] -= l;
}

extern "C" void kernel_launch(void* const* d_in, const int* in_sizes, int n_in,
                              void* d_out, int out_size, void* d_ws, size_t ws_size,
                              hipStream_t stream)
{
  (void)in_sizes; (void)n_in; (void)out_size; (void)ws_size;
  const float* x    = (const float*)d_in[0];
  const float* hp   = (const float*)d_in[1];
  const float* cp   = (const float*)d_in[2];
  const float* op   = (const float*)d_in[3];
  const float* enc  = (const float*)d_in[4];
  const float* Wih  = (const float*)d_in[5];
  const float* Whh  = (const float*)d_in[6];
  const float* bih  = (const float*)d_in[7];
  const float* bhh  = (const float*)d_in[8];
  const float* Wq   = (const float*)d_in[9];
  const float* Wm   = (const float*)d_in[10];
  const float* Wa   = (const float*)d_in[11];
  const float* Wo   = (const float*)d_in[12];
  const float* Wout = (const float*)d_in[13];
  float* out = (float*)d_out;

  float* ws = (float*)d_ws;
  float* gates   = ws + 0;                               // 262144
  float* qbuf    = ws + 262144;                          // 65536
  float* spb     = ws + 458752;                          // 524288 = [4][128*1024]
  float* ctxb    = ws + 983040;                          // 65536
  float* oaccb   = ws + 1048576;                         // 65536
  unsigned short* onbf = (unsigned short*)(ws + 1114112);// 65536 bf16 (32768 f32 slots)

  float* out_logits = out;                 // 4,096,000
  float* out_hn = out + 4096000;           // 65,536
  float* out_cn = out + 4161536;           // 65,536
  float* out_on = out + 4227072;           // 65,536
  float* out_w  = out + 4292608;           // 131,072

  hipMemsetAsync(gates, 0, (size_t)(262144 + 65536)*sizeof(float), stream); // gates + q
  hipMemsetAsync(ctxb, 0, (size_t)(65536 + 65536)*sizeof(float), stream);   // ctx + oacc

  sgemm_acc<<<dim3(64, 4), 256, 0, stream>>>(0, x, op, hp, Wih, Whh, gates, 2048, 320);
  lstm_act<<<256, 256, 0, stream>>>(gates, bih, bhh, cp, out_hn, out_cn);
  sgemm_acc<<<dim3(16, 8), 256, 0, stream>>>(1, out_hn, nullptr, nullptr, Wq, nullptr, qbuf, 512, 64);
  attn_gemm<<<4096, 256, 0, stream>>>(enc, Wm, qbuf, Wa, spb);
  attn_sm_ctx<<<1024, 512, 0, stream>>>(spb, enc, out_w, ctxb);
  sgemm_acc<<<dim3(16, 8), 256, 0, stream>>>(2, out_hn, ctxb, nullptr, Wo, nullptr, oaccb, 512, 128);
  tanh_act<<<256, 256, 0, stream>>>(oaccb, out_on, onbf);
  head_gemm<<<1000, 256, 0, stream>>>(onbf, Wout, out_logits);
  lse_fused<<<128, 1024, 0, stream>>>(out_logits);
}